// Round 3
// baseline (240.502 us; speedup 1.0000x reference)
//
#include <hip/hip_runtime.h>

#define Bn 2
#define Nn 4096
#define Cn 256
#define Kn 64
#define BK (Bn * Kn)
#define S 16
#define SEG (Nn / S)          // 256 points per segment: one per thread

// Fused: grid (BK, S). Each block pools one segment of one box; the last
// block to arrive per box does the segment-reduce + 2-layer MLP inline.
__global__ __launch_bounds__(256) void roi_fused_kernel(
    const float* __restrict__ points,      // (B,N,3)
    const float* __restrict__ feats,       // (B,N,C)
    const float* __restrict__ proposals,   // (B,K,7)
    const float* __restrict__ W1,          // (C,256)
    const float* __restrict__ b1,
    const float* __restrict__ W2,          // (256,256)
    const float* __restrict__ b2,
    float* __restrict__ out,               // (B,K,256)
    int*   __restrict__ arrival,           // (BK) zeroed before launch
    float* __restrict__ partial)           // (BK, S, 256)
{
    const int bk  = blockIdx.x;
    const int s   = blockIdx.y;
    const int b   = bk / Kn;
    const int tid = threadIdx.x;

    __shared__ int   s_idx[SEG];
    __shared__ int   s_count;
    __shared__ int   s_last;
    __shared__ float s_vec[Cn];

    // --- box bounds (strict inequalities; ry ignored, matches reference) ---
    const float* prop = proposals + (size_t)bk * 7;
    const float cx = prop[0], cy = prop[1], cz = prop[2];
    const float hx = prop[3] * 0.5f, hy = prop[4] * 0.5f, hz = prop[5] * 0.5f;
    const float lox = cx - hx, loy = cy - hy, loz = cz - hz;
    const float hix = cx + hx, hiy = cy + hy, hiz = cz + hz;

    if (tid == 0) s_count = 0;
    __syncthreads();

    // --- mask + compact: exactly one point per thread ---
    const float* pts = points + (size_t)b * Nn * 3;
    const int n = s * SEG + tid;
    {
        const float px = pts[n * 3 + 0];
        const float py = pts[n * 3 + 1];
        const float pz = pts[n * 3 + 2];
        const bool in = (px > lox) & (px < hix) &
                        (py > loy) & (py < hiy) &
                        (pz > loz) & (pz < hiz);
        if (in) s_idx[atomicAdd(&s_count, 1)] = n;
    }
    __syncthreads();
    const int count = s_count;

    // --- per-channel max over compacted indices (coalesced feature rows) ---
    const float* fb = feats + (size_t)b * Nn * Cn;
    float m = -INFINITY;
    int i = 0;
    for (; i + 4 <= count; i += 4) {
        const int a0 = s_idx[i + 0], a1 = s_idx[i + 1];
        const int a2 = s_idx[i + 2], a3 = s_idx[i + 3];
        const float f0 = fb[(size_t)a0 * Cn + tid];
        const float f1 = fb[(size_t)a1 * Cn + tid];
        const float f2 = fb[(size_t)a2 * Cn + tid];
        const float f3 = fb[(size_t)a3 * Cn + tid];
        m = fmaxf(m, fmaxf(fmaxf(f0, f1), fmaxf(f2, f3)));
    }
    for (; i < count; ++i) m = fmaxf(m, fb[(size_t)s_idx[i] * Cn + tid]);

    partial[((size_t)bk * S + s) * Cn + tid] = m;   // -inf if segment empty

    // --- arrive; last block per bk proceeds to reduce + MLP ---
    __threadfence();                 // partial write visible device-wide
    __syncthreads();
    if (tid == 0) s_last = (atomicAdd(&arrival[bk], 1) == S - 1);
    __syncthreads();
    if (!s_last) return;
    __threadfence();                 // acquire: see all other partials

    float mm = m;                    // own partial already in register
    const float* pp = partial + (size_t)bk * S * Cn + tid;
    #pragma unroll
    for (int ss = 0; ss < S; ++ss) mm = fmaxf(mm, pp[ss * Cn]);
    if (mm == -INFINITY) mm = 0.0f;  // empty box -> 0
    s_vec[tid] = mm;
    __syncthreads();

    float acc = b1[tid];
    #pragma unroll 16
    for (int c = 0; c < Cn; ++c) acc = fmaf(s_vec[c], W1[c * 256 + tid], acc);
    const float h = fmaxf(acc, 0.0f);
    __syncthreads();
    s_vec[tid] = h;
    __syncthreads();

    float acc2 = b2[tid];
    #pragma unroll 16
    for (int c = 0; c < 256; ++c) acc2 = fmaf(s_vec[c], W2[c * 256 + tid], acc2);
    out[(size_t)bk * 256 + tid] = fmaxf(acc2, 0.0f);
}

extern "C" void kernel_launch(void* const* d_in, const int* in_sizes, int n_in,
                              void* d_out, int out_size, void* d_ws, size_t ws_size,
                              hipStream_t stream) {
    const float* points    = (const float*)d_in[0];
    const float* feats     = (const float*)d_in[1];
    const float* proposals = (const float*)d_in[2];
    const float* W1        = (const float*)d_in[3];
    const float* b1        = (const float*)d_in[4];
    const float* W2        = (const float*)d_in[5];
    const float* b2        = (const float*)d_in[6];
    float* out             = (float*)d_out;

    int*   arrival = (int*)d_ws;                       // BK ints
    float* partial = (float*)((char*)d_ws + 4096);     // (BK,S,256) floats

    hipMemsetAsync(arrival, 0, BK * sizeof(int), stream);

    dim3 grid(BK, S);
    roi_fused_kernel<<<grid, 256, 0, stream>>>(points, feats, proposals,
                                               W1, b1, W2, b2, out,
                                               arrival, partial);
}

// Round 4
// 92.405 us; speedup vs baseline: 2.6027x; 2.6027x over previous
//
#include <hip/hip_runtime.h>

#define Bn 2
#define Nn 4096
#define Cn 256
#define Kn 64
#define BK (Bn * Kn)
#define NT 1024
#define NG 4                 // 4 groups x 256 channels
#define CG (Cn / NG)         // 64 c's per group in MLP split

// One block per (b,k). 1024 threads = 4 groups of 256.
// No cross-block communication; no device fences (R3 lesson: __threadfence
// L2 writeback serialized 2048 blocks -> 174us).
__global__ __launch_bounds__(NT) void roi_onepass_kernel(
    const float* __restrict__ points,      // (B,N,3)
    const float* __restrict__ feats,       // (B,N,C)
    const float* __restrict__ proposals,   // (B,K,7)
    const float* __restrict__ W1,          // (C,256)
    const float* __restrict__ b1,
    const float* __restrict__ W2,          // (256,256)
    const float* __restrict__ b2,
    float* __restrict__ out)               // (B,K,256)
{
    const int bk   = blockIdx.x;
    const int b    = bk / Kn;
    const int tid  = threadIdx.x;
    const int lane = tid & (Cn - 1);       // channel / neuron
    const int grp  = tid >> 8;             // 0..3

    __shared__ int   s_idx[Nn];            // 16 KiB compact list
    __shared__ int   s_count;
    __shared__ float s_red[NG][Cn];        // 4 KiB partials
    __shared__ float s_vec[Cn];            // pooled, then h

    // --- box bounds (strict inequalities; ry ignored, matches reference) ---
    const float* prop = proposals + (size_t)bk * 7;
    const float cx = prop[0], cy = prop[1], cz = prop[2];
    const float hx = prop[3] * 0.5f, hy = prop[4] * 0.5f, hz = prop[5] * 0.5f;
    const float lox = cx - hx, loy = cy - hy, loz = cz - hz;
    const float hix = cx + hx, hiy = cy + hy, hiz = cz + hz;

    if (tid == 0) s_count = 0;
    __syncthreads();

    // --- mask + compact: 4 points per thread ---
    const float* pts = points + (size_t)b * Nn * 3;
    #pragma unroll
    for (int n = tid; n < Nn; n += NT) {
        const float px = pts[n * 3 + 0];
        const float py = pts[n * 3 + 1];
        const float pz = pts[n * 3 + 2];
        const bool in = (px > lox) & (px < hix) &
                        (py > loy) & (py < hiy) &
                        (pz > loz) & (pz < hiz);
        if (in) s_idx[atomicAdd(&s_count, 1)] = n;
    }
    __syncthreads();
    const int count = s_count;

    // --- pooling: group g takes a contiguous quarter of the list ---
    const int i0 = (count * grp)       / NG;
    const int i1 = (count * (grp + 1)) / NG;
    const float* fb = feats + (size_t)b * Nn * Cn + lane;

    float m = -INFINITY;
    int i = i0;
    for (; i + 8 <= i1; i += 8) {          // 8 independent loads per batch
        const int a0 = s_idx[i + 0], a1 = s_idx[i + 1];
        const int a2 = s_idx[i + 2], a3 = s_idx[i + 3];
        const int a4 = s_idx[i + 4], a5 = s_idx[i + 5];
        const int a6 = s_idx[i + 6], a7 = s_idx[i + 7];
        const float f0 = fb[(size_t)a0 * Cn];
        const float f1 = fb[(size_t)a1 * Cn];
        const float f2 = fb[(size_t)a2 * Cn];
        const float f3 = fb[(size_t)a3 * Cn];
        const float f4 = fb[(size_t)a4 * Cn];
        const float f5 = fb[(size_t)a5 * Cn];
        const float f6 = fb[(size_t)a6 * Cn];
        const float f7 = fb[(size_t)a7 * Cn];
        m = fmaxf(m, fmaxf(fmaxf(fmaxf(f0, f1), fmaxf(f2, f3)),
                           fmaxf(fmaxf(f4, f5), fmaxf(f6, f7))));
    }
    for (; i < i1; ++i) m = fmaxf(m, fb[(size_t)s_idx[i] * Cn]);

    s_red[grp][lane] = m;
    __syncthreads();

    float mm = fmaxf(fmaxf(s_red[0][lane], s_red[1][lane]),
                     fmaxf(s_red[2][lane], s_red[3][lane]));
    if (count == 0) mm = 0.0f;             // empty box -> 0
    if (grp == 0) s_vec[lane] = mm;
    __syncthreads();

    // --- layer 1: K split 4-ways across groups ---
    {
        const int c0 = grp * CG;
        float acc = 0.0f;
        #pragma unroll 16
        for (int j = 0; j < CG; ++j) {
            const int c = c0 + j;
            acc = fmaf(s_vec[c], W1[c * Cn + lane], acc);
        }
        s_red[grp][lane] = acc;
    }
    __syncthreads();
    const float h = fmaxf(s_red[0][lane] + s_red[1][lane] +
                          s_red[2][lane] + s_red[3][lane] + b1[lane], 0.0f);
    __syncthreads();                       // all reads of s_red/h done
    if (grp == 0) s_vec[lane] = h;
    __syncthreads();

    // --- layer 2 ---
    {
        const int c0 = grp * CG;
        float acc = 0.0f;
        #pragma unroll 16
        for (int j = 0; j < CG; ++j) {
            const int c = c0 + j;
            acc = fmaf(s_vec[c], W2[c * Cn + lane], acc);
        }
        s_red[grp][lane] = acc;
    }
    __syncthreads();
    if (grp == 0) {
        const float o = fmaxf(s_red[0][lane] + s_red[1][lane] +
                              s_red[2][lane] + s_red[3][lane] + b2[lane], 0.0f);
        out[(size_t)bk * Cn + lane] = o;
    }
}

extern "C" void kernel_launch(void* const* d_in, const int* in_sizes, int n_in,
                              void* d_out, int out_size, void* d_ws, size_t ws_size,
                              hipStream_t stream) {
    const float* points    = (const float*)d_in[0];
    const float* feats     = (const float*)d_in[1];
    const float* proposals = (const float*)d_in[2];
    const float* W1        = (const float*)d_in[3];
    const float* b1        = (const float*)d_in[4];
    const float* W2        = (const float*)d_in[5];
    const float* b2        = (const float*)d_in[6];
    float* out             = (float*)d_out;

    roi_onepass_kernel<<<BK, NT, 0, stream>>>(points, feats, proposals,
                                              W1, b1, W2, b2, out);
}